// Round 12
// baseline (38.284 us; speedup 1.0000x reference)
//
#include <hip/hip_runtime.h>
#include <hip/hip_bf16.h>

#define N_SIDE 14
#define N_PATCH (N_SIDE * N_SIDE)   // 196
#define D_BB 384
#define DQ_BB (D_BB / 4)             // 96 float4 per cell
#define D_MODEL 512
#define CQ (D_MODEL / 4)             // 128 col-quads
#define BT_TOTAL 2048
#define LN_EPS 1e-5f
#define PGROUPS 8                    // pool cell groups (768 threads)

#define GROWS 8                      // rows per gemm block
#define GKP 8                        // K partitions (1 wave each)
#define GKCHUNK (D_BB / GKP)         // 48

__device__ __forceinline__ void fma4(float4& a, float s, const float4& wv) {
    a.x = fmaf(s, wv.x, a.x);
    a.y = fmaf(s, wv.y, a.y);
    a.z = fmaf(s, wv.z, a.z);
    a.w = fmaf(s, wv.w, a.w);
}

__device__ __forceinline__ void add4(float4& a, const float4& b) {
    a.x += b.x; a.y += b.y; a.z += b.z; a.w += b.w;
}

__device__ __forceinline__ void box_params(const float* __restrict__ bboxes, int bt,
                                           int& x1, int& y1, int& wd, int& total) {
    const float bx1 = bboxes[bt * 4 + 0];
    const float by1 = bboxes[bt * 4 + 1];
    const float bx2 = bboxes[bt * 4 + 2];
    const float by2 = bboxes[bt * 4 + 3];
    // match reference exactly: clip -> trunc/ceil -> clip -> max
    x1 = (int)fminf(fmaxf(bx1 * (float)N_SIDE, 0.f), (float)(N_SIDE - 1));
    y1 = (int)fminf(fmaxf(by1 * (float)N_SIDE, 0.f), (float)(N_SIDE - 1));
    int x2 = (int)fminf(fmaxf(ceilf(fminf(fmaxf(bx2 * (float)N_SIDE, 0.f), (float)N_SIDE)), 1.f), (float)N_SIDE);
    int y2 = (int)fminf(fmaxf(ceilf(fminf(fmaxf(by2 * (float)N_SIDE, 0.f), (float)N_SIDE)), 1.f), (float)N_SIDE);
    x2 = max(x2, x1 + 1);
    y2 = max(y2, y1 + 1);
    wd = x2 - x1;
    total = wd * (y2 - y1);
}

// ---------------- Kernel 1: ROI mean pool (unchanged: 768 thr, 8 groups, 4-deep) ----------------
__global__ __launch_bounds__(768) void pool_kernel(
    const float* __restrict__ patch,   // [BT,196,384]
    const float* __restrict__ bboxes,  // [BT,4]
    float* __restrict__ pooled)        // [BT,384] means
{
    const int bt = blockIdx.x;
    const int t  = threadIdx.x;
    const int qd = t % DQ_BB;   // channel quad 0..95
    const int g  = t / DQ_BB;   // cell group 0..7

    int x1, y1, wd, total;
    box_params(bboxes, bt, x1, y1, wd, total);
    const float inv_count = 1.f / (float)total;
    const float inv_wd = 1.f / (float)wd;
    const int cell0 = y1 * N_SIDE + x1;

    const float4* __restrict__ base = (const float4*)patch + (size_t)bt * N_PATCH * DQ_BB + qd;

    auto cell_off = [&](int c) -> size_t {
        const int y = (int)(((float)c + 0.5f) * inv_wd);
        const int x = c - y * wd;
        return (size_t)(cell0 + y * N_SIDE + x) * DQ_BB;
    };

    float4 acc = make_float4(0.f, 0.f, 0.f, 0.f);
    int c = g;
    for (; c + 3 * PGROUPS < total; c += 4 * PGROUPS) {
        const float4 v0 = base[cell_off(c)];
        const float4 v1 = base[cell_off(c + PGROUPS)];
        const float4 v2 = base[cell_off(c + 2 * PGROUPS)];
        const float4 v3 = base[cell_off(c + 3 * PGROUPS)];
        acc.x += (v0.x + v1.x) + (v2.x + v3.x);
        acc.y += (v0.y + v1.y) + (v2.y + v3.y);
        acc.z += (v0.z + v1.z) + (v2.z + v3.z);
        acc.w += (v0.w + v1.w) + (v2.w + v3.w);
    }
    for (; c < total; c += PGROUPS) {
        const float4 v = base[cell_off(c)];
        acc.x += v.x; acc.y += v.y; acc.z += v.z; acc.w += v.w;
    }

    __shared__ float4 part[PGROUPS][DQ_BB];   // 12 KB
    part[g][qd] = acc;
    __syncthreads();

    if (t < DQ_BB) {
        float4 s = part[0][t];
#pragma unroll
        for (int p = 1; p < PGROUPS; ++p) add4(s, part[p][t]);
        s.x *= inv_count; s.y *= inv_count; s.z *= inv_count; s.w *= inv_count;
        ((float4*)pooled)[(size_t)bt * DQ_BB + t] = s;
    }
}

// ---------------- Kernel 2 (v2 clean): LDS-free K-loop, 512 thr = 8 single-wave K-parts ----------------
// Lane owns col-quads jq and jq+64. A via SGPR s_load (wave-uniform addresses).
// W read exactly once per block (201 MB L2 total).
__global__ __launch_bounds__(512) void gemm_ln_kernel(
    const float* __restrict__ pooled,    // [BT,384] means
    const float* __restrict__ W,         // [384,512]
    const float* __restrict__ bias,      // [512]
    const float* __restrict__ gamma,     // [512]
    const float* __restrict__ beta,      // [512]
    const float* __restrict__ mask_tok,  // [512]
    const float* __restrict__ vis,       // [BT]
    float* __restrict__ out)             // [BT,512]
{
    const int tid = threadIdx.x;
    const int p   = tid >> 6;        // partition 0..7 (one wave)
    const int jq  = tid & 63;        // col-quad id; covers jq and jq+64
    const int r0  = blockIdx.x * GROWS;

    __shared__ float4 red4[4][GROWS][CQ];   // 64 KB tree buffer

    const float4* Wq = (const float4*)W;              // [384][128] float4
    const float*  A  = pooled + (size_t)r0 * D_BB;    // wave-uniform base

    float4 acc0[GROWS], acc1[GROWS];
#pragma unroll
    for (int r = 0; r < GROWS; ++r) {
        acc0[r] = make_float4(0.f, 0.f, 0.f, 0.f);
        acc1[r] = make_float4(0.f, 0.f, 0.f, 0.f);
    }

    // wave-uniform K base, forced into SGPR so A loads become s_load
    const int dbase = __builtin_amdgcn_readfirstlane(p * GKCHUNK);

#pragma unroll 2
    for (int i = 0; i < GKCHUNK / 4; ++i) {
        const int d = dbase + i * 4;
        const float4 w0a = Wq[(size_t)(d + 0) * CQ + jq];
        const float4 w0b = Wq[(size_t)(d + 0) * CQ + jq + 64];
        const float4 w1a = Wq[(size_t)(d + 1) * CQ + jq];
        const float4 w1b = Wq[(size_t)(d + 1) * CQ + jq + 64];
        const float4 w2a = Wq[(size_t)(d + 2) * CQ + jq];
        const float4 w2b = Wq[(size_t)(d + 2) * CQ + jq + 64];
        const float4 w3a = Wq[(size_t)(d + 3) * CQ + jq];
        const float4 w3b = Wq[(size_t)(d + 3) * CQ + jq + 64];
#pragma unroll
        for (int r = 0; r < GROWS; ++r) {
            const float* Ar = A + r * D_BB + d;   // uniform -> s_load_dwordx4
            const float a0 = Ar[0];
            const float a1 = Ar[1];
            const float a2 = Ar[2];
            const float a3 = Ar[3];
            fma4(acc0[r], a0, w0a); fma4(acc1[r], a0, w0b);
            fma4(acc0[r], a1, w1a); fma4(acc1[r], a1, w1b);
            fma4(acc0[r], a2, w2a); fma4(acc1[r], a2, w2b);
            fma4(acc0[r], a3, w3a); fma4(acc1[r], a3, w3b);
        }
    }

    // ---- cross-partition tree reduction: 8 -> 4 -> 2 -> 1 ----
    if (p >= 4) {
#pragma unroll
        for (int r = 0; r < GROWS; ++r) {
            red4[p - 4][r][jq]      = acc0[r];
            red4[p - 4][r][jq + 64] = acc1[r];
        }
    }
    __syncthreads();
    if (p < 4) {
#pragma unroll
        for (int r = 0; r < GROWS; ++r) {
            add4(acc0[r], red4[p][r][jq]);
            add4(acc1[r], red4[p][r][jq + 64]);
        }
    }
    __syncthreads();
    if (p == 2 || p == 3) {
#pragma unroll
        for (int r = 0; r < GROWS; ++r) {
            red4[p - 2][r][jq]      = acc0[r];
            red4[p - 2][r][jq + 64] = acc1[r];
        }
    }
    __syncthreads();
    if (p < 2) {
#pragma unroll
        for (int r = 0; r < GROWS; ++r) {
            add4(acc0[r], red4[p][r][jq]);
            add4(acc1[r], red4[p][r][jq + 64]);
        }
    }
    __syncthreads();
    if (p == 1) {
#pragma unroll
        for (int r = 0; r < GROWS; ++r) {
            red4[0][r][jq]      = acc0[r];
            red4[0][r][jq + 64] = acc1[r];
        }
    }
    __syncthreads();

    // ---- epilogue: single wave (p==0) holds full 512-col rows ----
    if (p == 0) {
        const float4 bj0 = ((const float4*)bias)[jq];
        const float4 bj1 = ((const float4*)bias)[jq + 64];
        const float4 g0  = ((const float4*)gamma)[jq];
        const float4 g1  = ((const float4*)gamma)[jq + 64];
        const float4 b0  = ((const float4*)beta)[jq];
        const float4 b1  = ((const float4*)beta)[jq + 64];
        const float4 m0  = ((const float4*)mask_tok)[jq];
        const float4 m1  = ((const float4*)mask_tok)[jq + 64];

#pragma unroll
        for (int r = 0; r < GROWS; ++r) {
            add4(acc0[r], red4[0][r][jq]);
            add4(acc1[r], red4[0][r][jq + 64]);
            add4(acc0[r], bj0);
            add4(acc1[r], bj1);

            float s  = acc0[r].x + acc0[r].y + acc0[r].z + acc0[r].w +
                       acc1[r].x + acc1[r].y + acc1[r].z + acc1[r].w;
            float s2 = acc0[r].x * acc0[r].x + acc0[r].y * acc0[r].y +
                       acc0[r].z * acc0[r].z + acc0[r].w * acc0[r].w +
                       acc1[r].x * acc1[r].x + acc1[r].y * acc1[r].y +
                       acc1[r].z * acc1[r].z + acc1[r].w * acc1[r].w;
#pragma unroll
            for (int off = 32; off >= 1; off >>= 1) {
                s  += __shfl_xor(s,  off);
                s2 += __shfl_xor(s2, off);
            }
            const float mean = s * (1.f / (float)D_MODEL);
            const float var  = s2 * (1.f / (float)D_MODEL) - mean * mean;
            const float rstd = rsqrtf(var + LN_EPS);
            const float v    = vis[r0 + r];
            const float iv   = 1.f - v;

            float4 o0, o1;
            o0.x = v * ((acc0[r].x - mean) * rstd * g0.x + b0.x) + iv * m0.x;
            o0.y = v * ((acc0[r].y - mean) * rstd * g0.y + b0.y) + iv * m0.y;
            o0.z = v * ((acc0[r].z - mean) * rstd * g0.z + b0.z) + iv * m0.z;
            o0.w = v * ((acc0[r].w - mean) * rstd * g0.w + b0.w) + iv * m0.w;
            o1.x = v * ((acc1[r].x - mean) * rstd * g1.x + b1.x) + iv * m1.x;
            o1.y = v * ((acc1[r].y - mean) * rstd * g1.y + b1.y) + iv * m1.y;
            o1.z = v * ((acc1[r].z - mean) * rstd * g1.z + b1.z) + iv * m1.z;
            o1.w = v * ((acc1[r].w - mean) * rstd * g1.w + b1.w) + iv * m1.w;
            ((float4*)out)[(size_t)(r0 + r) * CQ + jq]      = o0;
            ((float4*)out)[(size_t)(r0 + r) * CQ + jq + 64] = o1;
        }
    }
}

extern "C" void kernel_launch(void* const* d_in, const int* in_sizes, int n_in,
                              void* d_out, int out_size, void* d_ws, size_t ws_size,
                              hipStream_t stream) {
    const float* patch  = (const float*)d_in[0];  // [2048,196,384]
    const float* bboxes = (const float*)d_in[1];  // [2048,4]
    const float* vis    = (const float*)d_in[2];  // [2048]
    // d_in[3] = B, d_in[4] = T (scalars, unused)
    const float* W      = (const float*)d_in[5];  // [384,512]
    const float* bias   = (const float*)d_in[6];  // [512]
    const float* gamma  = (const float*)d_in[7];  // [512]
    const float* beta   = (const float*)d_in[8];  // [512]
    const float* mtok   = (const float*)d_in[9];  // [1,512]

    float* pooled = (float*)d_ws;                 // [2048,384] means, 3 MB
    float* out    = (float*)d_out;

    pool_kernel<<<BT_TOTAL, 768, 0, stream>>>(patch, bboxes, pooled);
    gemm_ln_kernel<<<BT_TOTAL / GROWS, 512, 0, stream>>>(
        pooled, W, bias, gamma, beta, mtok, vis, out);
}